// Round 2
// baseline (193.198 us; speedup 1.0000x reference)
//
#include <hip/hip_runtime.h>

// Gaussian covariance-from-scaling+quaternion, 4 gaussians per thread.
//   s = exp(scaling_raw); R = quat_to_rot(normalize(rotation));
//   L = R * diag(s); cov = L L^T; out = 6 upper-tri elems.
// Memory-bound (28 B in + 24 B out per gaussian). Round-1 profile showed
// latency-bound at 30% HBM peak (VGPR=20, no ILP). This version issues
// 7 float4 loads per thread up front, computes 4 covariances, stores 6
// float4s — 3.25 mem instrs/gaussian, all 16 B/lane.

__device__ __forceinline__ void cov6(float w, float x, float y, float z,
                                     float s0, float s1, float s2,
                                     float* __restrict__ c) {
    float inv = rsqrtf(w * w + x * x + y * y + z * z);
    w *= inv; x *= inv; y *= inv; z *= inv;
    float xx = x * x, yy = y * y, zz = z * z;
    float xy = x * y, xz = x * z, yz = y * z;
    float wx = w * x, wy = w * y, wz = w * z;
    float L00 = (1.f - 2.f * (yy + zz)) * s0, L01 = 2.f * (xy - wz) * s1, L02 = 2.f * (xz + wy) * s2;
    float L10 = 2.f * (xy + wz) * s0, L11 = (1.f - 2.f * (xx + zz)) * s1, L12 = 2.f * (yz - wx) * s2;
    float L20 = 2.f * (xz - wy) * s0, L21 = 2.f * (yz + wx) * s1, L22 = (1.f - 2.f * (xx + yy)) * s2;
    c[0] = L00 * L00 + L01 * L01 + L02 * L02;
    c[1] = L00 * L10 + L01 * L11 + L02 * L12;
    c[2] = L00 * L20 + L01 * L21 + L02 * L22;
    c[3] = L10 * L10 + L11 * L11 + L12 * L12;
    c[4] = L10 * L20 + L11 * L21 + L12 * L22;
    c[5] = L20 * L20 + L21 * L21 + L22 * L22;
}

__global__ __launch_bounds__(256) void gauss_cov4_kernel(
    const float4* __restrict__ sr4,   // (N*3/4) float4 view of scaling_raw
    const float4* __restrict__ rot,   // (N) float4 quaternions
    float4* __restrict__ out4,        // (N*6/4) float4 view of output
    const float* __restrict__ sr,     // scalar views for the tail path
    float* __restrict__ out,
    int n)
{
    int t = blockIdx.x * 256 + threadIdx.x;
    long long g = (long long)t * 4;
    if (g + 3 < n) {
        // scaling: 12 contiguous floats = 3 aligned float4 loads
        float4 a = sr4[3 * (size_t)t];
        float4 b = sr4[3 * (size_t)t + 1];
        float4 d = sr4[3 * (size_t)t + 2];
        // rotations: 4 aligned float4 loads
        float4 q0 = rot[g], q1 = rot[g + 1], q2 = rot[g + 2], q3 = rot[g + 3];

        float e0  = __expf(a.x), e1  = __expf(a.y), e2  = __expf(a.z);
        float e3  = __expf(a.w), e4  = __expf(b.x), e5  = __expf(b.y);
        float e6  = __expf(b.z), e7  = __expf(b.w), e8  = __expf(d.x);
        float e9  = __expf(d.y), e10 = __expf(d.z), e11 = __expf(d.w);

        float c[24];
        cov6(q0.x, q0.y, q0.z, q0.w, e0, e1, e2, c + 0);
        cov6(q1.x, q1.y, q1.z, q1.w, e3, e4, e5, c + 6);
        cov6(q2.x, q2.y, q2.z, q2.w, e6, e7, e8, c + 12);
        cov6(q3.x, q3.y, q3.z, q3.w, e9, e10, e11, c + 18);

        float4* o = out4 + 6 * (size_t)t;
        #pragma unroll
        for (int j = 0; j < 6; ++j)
            o[j] = make_float4(c[4 * j], c[4 * j + 1], c[4 * j + 2], c[4 * j + 3]);
    } else if (g < n) {
        // scalar tail (only if n % 4 != 0 or last partial thread)
        for (long long i = g; i < n; ++i) {
            float4 q = rot[i];
            float e0 = __expf(sr[3 * i]), e1 = __expf(sr[3 * i + 1]), e2 = __expf(sr[3 * i + 2]);
            float c[6];
            cov6(q.x, q.y, q.z, q.w, e0, e1, e2, c);
            #pragma unroll
            for (int j = 0; j < 6; ++j) out[6 * i + j] = c[j];
        }
    }
}

extern "C" void kernel_launch(void* const* d_in, const int* in_sizes, int n_in,
                              void* d_out, int out_size, void* d_ws, size_t ws_size,
                              hipStream_t stream) {
    const float*  sr  = (const float*)d_in[0];   // (N,3)
    const float4* rot = (const float4*)d_in[1];  // (N,4)
    float* out = (float*)d_out;                  // (N,6)
    int n = in_sizes[0] / 3;

    int nthreads = (n + 3) / 4;
    int grid = (nthreads + 255) / 256;
    gauss_cov4_kernel<<<grid, 256, 0, stream>>>(
        (const float4*)sr, rot, (float4*)out, sr, out, n);
}

// Round 8
// 182.465 us; speedup vs baseline: 1.0588x; 1.0588x over previous
//
#include <hip/hip_runtime.h>

// Gaussian covariance: s=exp(scaling); R=quat2rot(normalize(q)); cov=R diag(s^2) R^T.
// R8 (= R4 resubmit; four broker timeouts): LDS-staged layout transpose so ALL
// global traffic is coalesced float4 (R1/R2 were transaction-bound at ~30% HBM
// peak from strided AoS access). Block = 256 threads / 512 gaussians / 14 KiB
// LDS; 2 gaussians per thread. Nontemporal store via native ext_vector type.

#define TPB 256
#define GPB 512               // gaussians per block
#define SC_SLOTS 384          // 512*3 floats  = 384 float4
#define ROT_SLOTS 512         // 512*4 floats  = 512 float4
#define OUT_SLOTS 768         // 512*6 floats  = 768 float4

typedef float f32x4 __attribute__((ext_vector_type(4)));

__device__ __forceinline__ void cov6(float w, float x, float y, float z,
                                     float s0, float s1, float s2,
                                     float* __restrict__ c) {
    float inv = rsqrtf(w * w + x * x + y * y + z * z);
    w *= inv; x *= inv; y *= inv; z *= inv;
    float xx = x * x, yy = y * y, zz = z * z;
    float xy = x * y, xz = x * z, yz = y * z;
    float wx = w * x, wy = w * y, wz = w * z;
    float L00 = (1.f - 2.f * (yy + zz)) * s0, L01 = 2.f * (xy - wz) * s1, L02 = 2.f * (xz + wy) * s2;
    float L10 = 2.f * (xy + wz) * s0, L11 = (1.f - 2.f * (xx + zz)) * s1, L12 = 2.f * (yz - wx) * s2;
    float L20 = 2.f * (xz - wy) * s0, L21 = 2.f * (yz + wx) * s1, L22 = (1.f - 2.f * (xx + yy)) * s2;
    c[0] = L00 * L00 + L01 * L01 + L02 * L02;
    c[1] = L00 * L10 + L01 * L11 + L02 * L12;
    c[2] = L00 * L20 + L01 * L21 + L02 * L22;
    c[3] = L10 * L10 + L11 * L11 + L12 * L12;
    c[4] = L10 * L20 + L11 * L21 + L12 * L22;
    c[5] = L20 * L20 + L21 * L21 + L22 * L22;
}

__global__ __launch_bounds__(TPB, 8) void gauss_cov_lds(
    const float4* __restrict__ sr4,   // scaling_raw as N*3/4 float4
    const float4* __restrict__ rot4,  // rotation as N float4
    float4* __restrict__ out4,        // out as N*6/4 float4
    int n)
{
    __shared__ float4 lds[SC_SLOTS + ROT_SLOTS];   // 896 * 16 B = 14336 B
    const int tid = threadIdx.x;

    const long long sc_total  = (long long)n * 3 / 4;
    const long long out_total = (long long)n * 6 / 4;

    // ---- stage: perfectly coalesced global float4 loads -> LDS ----
    {
        const long long sb = (long long)blockIdx.x * SC_SLOTS;
        #pragma unroll
        for (int k = 0; k < 2; ++k) {            // 384 slots
            int j = tid + k * TPB;
            if (j < SC_SLOTS && sb + j < sc_total)
                lds[j] = sr4[sb + j];
        }
        const long long rb = (long long)blockIdx.x * GPB;
        #pragma unroll
        for (int k = 0; k < 2; ++k) {            // 512 slots; source pre-swizzled
            int j = tid + k * TPB;
            int js = j ^ ((j >> 3) & 7);         // XOR involution within 512-window
            if (rb + js < (long long)n)
                lds[SC_SLOTS + j] = rot4[rb + js];
        }
    }
    __syncthreads();

    // ---- gather my 2 gaussians from LDS ----
    const float* ldsf = (const float*)lds;
    float2 sa = *(const float2*)(ldsf + 6 * tid);      // 8B-aligned (24t)
    float2 sbv = *(const float2*)(ldsf + 6 * tid + 2);
    float2 sc = *(const float2*)(ldsf + 6 * tid + 4);
    int r0 = 2 * tid, r1 = 2 * tid + 1;
    float4 q0 = lds[SC_SLOTS + (r0 ^ ((r0 >> 3) & 7))];  // swizzled -> bank-minimal
    float4 q1 = lds[SC_SLOTS + (r1 ^ ((r1 >> 3) & 7))];
    __syncthreads();   // all input reads done; LDS reusable for output

    // ---- compute (registers only) ----
    float e0 = __expf(sa.x), e1 = __expf(sa.y), e2 = __expf(sbv.x);
    float e3 = __expf(sbv.y), e4 = __expf(sc.x), e5 = __expf(sc.y);
    float c[12];
    cov6(q0.x, q0.y, q0.z, q0.w, e0, e1, e2, c);
    cov6(q1.x, q1.y, q1.z, q1.w, e3, e4, e5, c + 6);

    // ---- scatter to LDS (float4-aligned, bank-balanced), then coalesced store ----
    float* outf = (float*)lds;
    *(float4*)(outf + 12 * tid + 0) = make_float4(c[0], c[1], c[2],  c[3]);
    *(float4*)(outf + 12 * tid + 4) = make_float4(c[4], c[5], c[6],  c[7]);
    *(float4*)(outf + 12 * tid + 8) = make_float4(c[8], c[9], c[10], c[11]);
    __syncthreads();

    const long long ob = (long long)blockIdx.x * OUT_SLOTS;
    const f32x4* ldsn = (const f32x4*)lds;
    f32x4* outn = (f32x4*)out4;
    #pragma unroll
    for (int k = 0; k < 3; ++k) {                // 768 slots
        int j = tid + k * TPB;
        if (ob + j < out_total)
            __builtin_nontemporal_store(ldsn[j], &outn[ob + j]);
    }
}

extern "C" void kernel_launch(void* const* d_in, const int* in_sizes, int n_in,
                              void* d_out, int out_size, void* d_ws, size_t ws_size,
                              hipStream_t stream) {
    const float4* sr4  = (const float4*)d_in[0];  // (N,3) f32, N*3 % 4 == 0 (N even)
    const float4* rot4 = (const float4*)d_in[1];  // (N,4) f32
    float4* out4 = (float4*)d_out;                // (N,6) f32
    int n = in_sizes[0] / 3;

    int grid = (int)(((long long)n + GPB - 1) / GPB);
    gauss_cov_lds<<<grid, TPB, 0, stream>>>(sr4, rot4, out4, n);
}